// Round 5
// baseline (1029.759 us; speedup 1.0000x reference)
//
#include <hip/hip_runtime.h>

// ---------------------------------------------------------------------------
// SimplifiedMambaModel on MI355X (gfx950)
// B=32 T=2048 D=512 S=64 L=4 V=32000 C=2
//  - bf16 MFMA (16x16x32), fp32 accumulate, fused epilogues
//  - gateop: dbuf single-barrier pipeline; weights/hs read direct from L2
//    (no LDS staging for L2-resident data), only xn tile staged (swizzled)
//  - ln_u: fused LN + u-projection, 32-row blocks for occupancy
//  - tanh-RNN scan parallelized over 64-step chunks (16-step warmup, exact
//    to ~1e-11 by contraction sigma_max(A)~0.16)
// ---------------------------------------------------------------------------

#define DEV __device__ __forceinline__

typedef __attribute__((ext_vector_type(8))) short short8v;   // 8 x bf16
typedef __attribute__((ext_vector_type(4))) float f32x4;     // MFMA C/D frag

static constexpr int Bn = 32, Tn = 2048, Dn = 512, Sn = 64, Lk = 4;
static constexpr int Mrows = Bn * Tn;  // 65536

DEV unsigned short f2bf(float f) {          // RNE float->bf16
  unsigned u = __float_as_uint(f);
  u += 0x7fffu + ((u >> 16) & 1u);
  return (unsigned short)(u >> 16);
}
DEV float bf2f(unsigned short h) { return __uint_as_float(((unsigned)h) << 16); }

DEV void g2lds16(const void* g, void* l) {
  __builtin_amdgcn_global_load_lds(
      (const __attribute__((address_space(1))) void*)g,
      (__attribute__((address_space(3))) void*)l, 16, 0, 0);
}

// Stage a [ROWS x 64-bf16] tile with T2 XOR swizzle: LDS dest linear
// (global_load_lds requirement), global source column pre-swizzled so that
// LDS ushort (row, e) holds source element (row, e ^ ((row&7)<<3)).
// Readers XOR their FULL ushort column index with ((row&7)<<3).
template <int THREADS, int ROWS>
DEV void stage_sw(const char* gbase, size_t rowStride, size_t kOff, char* lds, int tid) {
#pragma unroll
  for (int r = 0; r < ROWS * 128 / (THREADS * 16); ++r) {
    int o = r * THREADS * 16 + tid * 16;
    int row = o >> 7, kb = o & 127;
    g2lds16(gbase + (size_t)row * rowStride + kOff + (size_t)(kb ^ ((row & 7) << 4)),
            lds + o);
  }
}

// ---------------------------------------------------------------------------
// Weight prep
// ---------------------------------------------------------------------------
__global__ void prep_wu(const float* __restrict__ Wsp, const float* __restrict__ Wip,
                        const float* __restrict__ bsp, const float* __restrict__ bip,
                        unsigned short* __restrict__ Wu, float* __restrict__ bu) {
  int i = blockIdx.x * 256 + threadIdx.x;
  if (i < Lk * Sn * Dn) Wu[i] = f2bf(Wsp[i] + Wip[i]);
  if (i < Lk * Sn) bu[i] = bsp[i] + bip[i];
}

__global__ void cast_bf(const float* __restrict__ src, unsigned short* __restrict__ dst, int n) {
  int i = blockIdx.x * 256 + threadIdx.x;
  if (i < n) dst[i] = f2bf(src[i]);
}

// ---------------------------------------------------------------------------
// Embedding gather: x[b,t,:] = emb[tok[b,t],:] * sqrt(512)
// ---------------------------------------------------------------------------
__global__ __launch_bounds__(256) void embed_kernel(const int* __restrict__ tok,
                                                    const float* __restrict__ emb,
                                                    float* __restrict__ x) {
  const float scale = sqrtf(512.0f);
  size_t i = (size_t)blockIdx.x * 256 + threadIdx.x;   // one float4 each
  int row = (int)(i >> 7);
  int c4  = (int)(i & 127);
  int t = tok[row];
  const float* src = emb + (size_t)t * Dn + c4 * 4;
  float4 v = *(const float4*)src;
  v.x *= scale; v.y *= scale; v.z *= scale; v.w *= scale;
  ((float4*)x)[i] = v;
}

// ---------------------------------------------------------------------------
// Fused LayerNorm + u-projection.  32 rows/block, 256 threads (4 waves).
//   xn = LN(x)*g+b (bf16, kept in 32KB LDS, swizzled);  u = xn @ Wu^T + bu
// Wu (64KB) read direct from L2.  5 blocks/CU -> 20 waves/CU.
// ---------------------------------------------------------------------------
__global__ __launch_bounds__(256) void ln_u_kernel(
    const float* __restrict__ x,            // [Mc,512]
    const float* __restrict__ lnw, const float* __restrict__ lnb,
    const unsigned short* __restrict__ Wu,  // [64,512] bf16
    const float* __restrict__ bu,           // [64]
    unsigned short* __restrict__ xn,        // [Mc,512] bf16 out
    float* __restrict__ u) {                // [Mc,64]  fp32 out
  __shared__ __align__(16) unsigned short As[32 * 512];   // 32KB, XOR-swizzled
  const int tid = threadIdx.x, lane = tid & 63, w = tid >> 6;
  const int row0 = blockIdx.x * 32;
  const float4* wp = (const float4*)(lnw + lane * 8);
  const float4* bp = (const float4*)(lnb + lane * 8);
  float4 g0 = wp[0], g1 = wp[1], be0 = bp[0], be1 = bp[1];

#pragma unroll 2
  for (int i = 0; i < 8; ++i) {
    int row = w * 8 + i;
    size_t grow = (size_t)(row0 + row);
    const float* xr = x + grow * 512 + lane * 8;
    float4 v0 = *(const float4*)xr;
    float4 v1 = *(const float4*)(xr + 4);
    float s = (v0.x + v0.y + v0.z + v0.w) + (v1.x + v1.y + v1.z + v1.w);
    float q = v0.x*v0.x + v0.y*v0.y + v0.z*v0.z + v0.w*v0.w
            + v1.x*v1.x + v1.y*v1.y + v1.z*v1.z + v1.w*v1.w;
#pragma unroll
    for (int m = 32; m >= 1; m >>= 1) { s += __shfl_xor(s, m); q += __shfl_xor(q, m); }
    float mean = s * (1.f / 512.f);
    float var  = q * (1.f / 512.f) - mean * mean;
    float rstd = 1.f / sqrtf(var + 1e-5f);
    short8v o;
    o[0] = (short)f2bf((v0.x - mean) * rstd * g0.x + be0.x);
    o[1] = (short)f2bf((v0.y - mean) * rstd * g0.y + be0.y);
    o[2] = (short)f2bf((v0.z - mean) * rstd * g0.z + be0.z);
    o[3] = (short)f2bf((v0.w - mean) * rstd * g0.w + be0.w);
    o[4] = (short)f2bf((v1.x - mean) * rstd * g1.x + be1.x);
    o[5] = (short)f2bf((v1.y - mean) * rstd * g1.y + be1.y);
    o[6] = (short)f2bf((v1.z - mean) * rstd * g1.z + be1.z);
    o[7] = (short)f2bf((v1.w - mean) * rstd * g1.w + be1.w);
    *(short8v*)&As[row * 512 + ((lane * 8) ^ ((row & 7) << 3))] = o;
    *(short8v*)(xn + grow * 512 + lane * 8) = o;
  }
  __syncthreads();

  // waves 2x2: wr=w>>1 rows, wc=w&1 cols (each 16r x 32c output)
  const int wr = w >> 1, wc = w & 1;
  f32x4 acc[2] = {};
  const int rs = lane & 15, kx = (lane >> 4) * 8;
  const int key = (rs & 7) << 3;
  const int arow = (wr * 16 + rs) * 512;
#pragma unroll
  for (int kt = 0; kt < 16; ++kt) {
    short8v a = *(const short8v*)&As[arow + ((kt * 32 + kx) ^ key)];
#pragma unroll
    for (int n = 0; n < 2; ++n) {
      int col = wc * 32 + n * 16 + rs;
      short8v b = *(const short8v*)(Wu + (size_t)col * 512 + kt * 32 + kx);
      acc[n] = __builtin_amdgcn_mfma_f32_16x16x32_bf16(a, b, acc[n], 0, 0, 0);
    }
  }
  const int ccol = lane & 15, cr4 = (lane >> 4) * 4;
#pragma unroll
  for (int n = 0; n < 2; ++n) {
    int col = wc * 32 + n * 16 + ccol;
    float bv = bu[col];
#pragma unroll
    for (int j = 0; j < 4; ++j) {
      int row = wr * 16 + cr4 + j;
      u[(size_t)(row0 + row) * 64 + col] = acc[n][j] + bv;
    }
  }
}

// ---------------------------------------------------------------------------
// Fused gate + out-projection + residual:
//   x[r,c] += sigmoid(xn@Wg^T + bg)[r,c] * (hs@Wop^T + bop)[r,c]
// BM=BN=128, 512 threads (8 waves, 2r x 4c; wave tile 64x32).
// xn tile double-buffered in LDS (single barrier per K-step, stage overlaps
// MFMA); Wg / Wop / hs fragments read DIRECT from global (L2/L3-resident).
// ---------------------------------------------------------------------------
__global__ __launch_bounds__(512) void gemm_gateop(
    const unsigned short* __restrict__ xn,   // [Mc,512] bf16
    const unsigned short* __restrict__ hs,   // [Mc,64]  bf16
    const unsigned short* __restrict__ Wg,   // [512,512] bf16
    const unsigned short* __restrict__ Wop,  // [512,64]  bf16
    const float* __restrict__ bg, const float* __restrict__ bop,
    float* __restrict__ xr) {                // [Mc,512] fp32 RMW
  __shared__ __align__(16) unsigned short As[2][128 * 64];   // 2 x 16KB dbuf
  const int tid = threadIdx.x, lane = tid & 63, wave = tid >> 6;
  const int wr = wave >> 2, wc = wave & 3;           // 2 x 4 waves
  const int row0 = blockIdx.x * 128, col0 = blockIdx.y * 128;
  f32x4 accg[4][2] = {};
  f32x4 acco[4][2] = {};
  const int rs = lane & 15, kx = (lane >> 4) * 8;
  const int swu = (rs & 7) << 3;

  const char* Ab = (const char*)(xn + (size_t)row0 * 512);

  // prologue: stage k-tile 0
  stage_sw<512, 128>(Ab, 1024, 0, (char*)As[0], tid);
  __syncthreads();

  int cur = 0;
  for (int kt = 0; kt < 8; ++kt) {
    if (kt < 7)   // stage next k-tile (overlaps this tile's MFMAs)
      stage_sw<512, 128>(Ab, 1024, (size_t)(kt + 1) * 128, (char*)As[cur ^ 1], tid);
#pragma unroll
    for (int kk = 0; kk < 2; ++kk) {
      const int ks = (kk * 32 + kx) ^ swu;
      short8v af[4], bfv[2];
#pragma unroll
      for (int m = 0; m < 4; ++m)
        af[m] = *(const short8v*)&As[cur][(wr * 64 + m * 16 + rs) * 64 + ks];
#pragma unroll
      for (int n = 0; n < 2; ++n)
        bfv[n] = *(const short8v*)(Wg + (size_t)(col0 + wc * 32 + n * 16 + rs) * 512
                                     + kt * 64 + kk * 32 + kx);
#pragma unroll
      for (int m = 0; m < 4; ++m)
#pragma unroll
        for (int n = 0; n < 2; ++n)
          accg[m][n] = __builtin_amdgcn_mfma_f32_16x16x32_bf16(af[m], bfv[n], accg[m][n], 0, 0, 0);
    }
    __syncthreads();   // next buffer staged + everyone done with cur
    cur ^= 1;
  }

  // out-projection (K=64): hs and Wop fragments direct from global (L3-hot)
#pragma unroll
  for (int kk = 0; kk < 2; ++kk) {
    short8v af[4], bfv[2];
#pragma unroll
    for (int m = 0; m < 4; ++m)
      af[m] = *(const short8v*)(hs + (size_t)(row0 + wr * 64 + m * 16 + rs) * 64
                                  + kk * 32 + kx);
#pragma unroll
    for (int n = 0; n < 2; ++n)
      bfv[n] = *(const short8v*)(Wop + (size_t)(col0 + wc * 32 + n * 16 + rs) * 64
                                    + kk * 32 + kx);
#pragma unroll
    for (int m = 0; m < 4; ++m)
#pragma unroll
      for (int n = 0; n < 2; ++n)
        acco[m][n] = __builtin_amdgcn_mfma_f32_16x16x32_bf16(af[m], bfv[n], acco[m][n], 0, 0, 0);
  }

  // epilogue: C/D layout col=lane&15, row=(lane>>4)*4+reg
  const int ccol = lane & 15, cr4 = (lane >> 4) * 4;
#pragma unroll
  for (int m = 0; m < 4; ++m)
#pragma unroll
    for (int n = 0; n < 2; ++n) {
      int gcol = col0 + wc * 32 + n * 16 + ccol;
      float bgv = bg[gcol], bov = bop[gcol];
#pragma unroll
      for (int j = 0; j < 4; ++j) {
        int grow = row0 + wr * 64 + m * 16 + cr4 + j;
        size_t idx = (size_t)grow * 512 + gcol;
        float gv = 1.f / (1.f + __expf(-(accg[m][n][j] + bgv)));
        float ov = acco[m][n][j] + bov;
        xr[idx] += gv * ov;
      }
    }
}

// ---------------------------------------------------------------------------
// Chunked tanh-RNN scan: one wave per (batch, 64-step chunk), 16-step warmup.
// ---------------------------------------------------------------------------
__global__ __launch_bounds__(64) void scan_kernel(const float* __restrict__ u,
                                                  const float* __restrict__ A,
                                                  unsigned short* __restrict__ hs) {
  const int l = threadIdx.x;
  const int b = blockIdx.y, c = blockIdx.x;
  __shared__ float h[Sn];
  h[l] = 0.f;

  float4 Ar[16];
  const float4* Arow = (const float4*)(A + (size_t)l * Sn);
#pragma unroll
  for (int i = 0; i < 16; ++i) Ar[i] = Arow[i];

  int t0 = c * 64 - 16; if (t0 < 0) t0 = 0;
  const int tw = c * 64, tend = c * 64 + 64;
  const float* ub = u + (size_t)b * Tn * Sn;
  unsigned short* hb = hs + (size_t)b * Tn * Sn;

  float uv = ub[(size_t)t0 * Sn + l];
  for (int t = t0; t < tend; ++t) {
    int tnext = t + 1 < Tn ? t + 1 : Tn - 1;
    float unext = ub[(size_t)tnext * Sn + l];
    const float4* h4 = (const float4*)h;
    float a0 = uv, a1 = 0.f, a2 = 0.f, a3 = 0.f;
#pragma unroll
    for (int i = 0; i < 16; i += 4) {
      float4 h0 = h4[i], h1 = h4[i + 1], h2 = h4[i + 2], h3 = h4[i + 3];
      a0 += Ar[i].x * h0.x + Ar[i].y * h0.y + Ar[i].z * h0.z + Ar[i].w * h0.w;
      a1 += Ar[i+1].x * h1.x + Ar[i+1].y * h1.y + Ar[i+1].z * h1.z + Ar[i+1].w * h1.w;
      a2 += Ar[i+2].x * h2.x + Ar[i+2].y * h2.y + Ar[i+2].z * h2.z + Ar[i+2].w * h2.w;
      a3 += Ar[i+3].x * h3.x + Ar[i+3].y * h3.y + Ar[i+3].z * h3.z + Ar[i+3].w * h3.w;
    }
    float sv = (a0 + a1) + (a2 + a3);
    sv = fminf(fmaxf(sv, -15.f), 15.f);
    float e = __expf(2.f * sv);
    float hn = __fdividef(e - 1.f, e + 1.f);   // tanh
    if (t >= tw) hb[(size_t)t * Sn + l] = f2bf(hn);
    h[l] = hn;          // single-wave lockstep
    uv = unext;
  }
}

// ---------------------------------------------------------------------------
// Final LN + partial mean (deterministic two-stage)
// ---------------------------------------------------------------------------
__global__ __launch_bounds__(256) void final_ln_mean(const float* __restrict__ x,
                                                     const float* __restrict__ fw,
                                                     const float* __restrict__ fb,
                                                     float* __restrict__ part) {
  const int b = blockIdx.y, chunk = blockIdx.x;
  const int wave = threadIdx.x >> 6, lane = threadIdx.x & 63;
  const float4* wp = (const float4*)(fw + lane * 8);
  const float4* bp = (const float4*)(fb + lane * 8);
  float4 w0 = wp[0], w1 = wp[1], bb0 = bp[0], bb1 = bp[1];
  float acc[8] = {};
  for (int it = 0; it < 64; ++it) {
    int t = chunk * 256 + it * 4 + wave;
    const float* xr = x + ((size_t)b * Tn + t) * Dn + lane * 8;
    float4 v0 = *(const float4*)xr;
    float4 v1 = *(const float4*)(xr + 4);
    float s = (v0.x + v0.y + v0.z + v0.w) + (v1.x + v1.y + v1.z + v1.w);
#pragma unroll
    for (int m = 32; m >= 1; m >>= 1) s += __shfl_xor(s, m);
    float mean = s * (1.f / 512.f);
    float d0 = v0.x - mean, d1 = v0.y - mean, d2 = v0.z - mean, d3 = v0.w - mean;
    float d4 = v1.x - mean, d5 = v1.y - mean, d6 = v1.z - mean, d7 = v1.w - mean;
    float q = d0*d0 + d1*d1 + d2*d2 + d3*d3 + d4*d4 + d5*d5 + d6*d6 + d7*d7;
#pragma unroll
    for (int m = 32; m >= 1; m >>= 1) q += __shfl_xor(q, m);
    float rstd = 1.f / sqrtf(q * (1.f / 512.f) + 1e-5f);
    acc[0] += d0 * rstd * w0.x + bb0.x;
    acc[1] += d1 * rstd * w0.y + bb0.y;
    acc[2] += d2 * rstd * w0.z + bb0.z;
    acc[3] += d3 * rstd * w0.w + bb0.w;
    acc[4] += d4 * rstd * w1.x + bb1.x;
    acc[5] += d5 * rstd * w1.y + bb1.y;
    acc[6] += d6 * rstd * w1.z + bb1.z;
    acc[7] += d7 * rstd * w1.w + bb1.w;
  }
  __shared__ float red[4][512];
#pragma unroll
  for (int j = 0; j < 8; ++j) red[wave][lane * 8 + j] = acc[j];
  __syncthreads();
#pragma unroll
  for (int cc = 0; cc < 2; ++cc) {
    int cidx = threadIdx.x * 2 + cc;
    part[((size_t)(chunk * Bn + b)) * Dn + cidx] =
        red[0][cidx] + red[1][cidx] + red[2][cidx] + red[3][cidx];
  }
}

__global__ __launch_bounds__(512) void reduce_y(const float* __restrict__ part,
                                                float* __restrict__ y) {
  int b = blockIdx.x, d = threadIdx.x;
  float s = 0.f;
#pragma unroll
  for (int ch = 0; ch < 8; ++ch) s += part[((size_t)(ch * Bn + b)) * Dn + d];
  y[b * Dn + d] = s * (1.f / 2048.f);
}

// ---------------------------------------------------------------------------
// Head: out[b,:] = relu(y @ W1^T + b1) @ W2^T + b2
// ---------------------------------------------------------------------------
__global__ __launch_bounds__(256) void head_kernel(const float* __restrict__ y,
                                                   const float* __restrict__ W1,
                                                   const float* __restrict__ b1,
                                                   const float* __restrict__ W2,
                                                   const float* __restrict__ b2,
                                                   float* __restrict__ out) {
  const int b = blockIdx.x, j = threadIdx.x;
  __shared__ float ybuf[Dn];
  ybuf[j] = y[(size_t)b * Dn + j];
  ybuf[j + 256] = y[(size_t)b * Dn + 256 + j];
  __syncthreads();
  const float4* wj = (const float4*)(W1 + (size_t)j * Dn);
  const float4* yb = (const float4*)ybuf;
  float a0 = 0.f, a1 = 0.f, a2 = 0.f, a3 = 0.f;
  for (int k = 0; k < 128; k += 4) {
    float4 q0 = wj[k], q1 = wj[k+1], q2 = wj[k+2], q3 = wj[k+3];
    float4 u0 = yb[k], u1 = yb[k+1], u2 = yb[k+2], u3 = yb[k+3];
    a0 += q0.x*u0.x + q0.y*u0.y + q0.z*u0.z + q0.w*u0.w;
    a1 += q1.x*u1.x + q1.y*u1.y + q1.z*u1.z + q1.w*u1.w;
    a2 += q2.x*u2.x + q2.y*u2.y + q2.z*u2.z + q2.w*u2.w;
    a3 += q3.x*u3.x + q3.y*u3.y + q3.z*u3.z + q3.w*u3.w;
  }
  float hv = fmaxf((a0 + a1) + (a2 + a3) + b1[j], 0.f);
  __shared__ float red[256];
  for (int c = 0; c < 2; ++c) {
    red[j] = hv * W2[c * 256 + j];
    __syncthreads();
    for (int s2 = 128; s2 > 0; s2 >>= 1) {
      if (j < s2) red[j] += red[j + s2];
      __syncthreads();
    }
    if (j == 0) out[b * 2 + c] = red[0] + b2[c];
    __syncthreads();
  }
}

// ---------------------------------------------------------------------------
// Workspace layout (bytes). Fixed region, then x (fp32), then chunk buffers.
// ---------------------------------------------------------------------------
static constexpr size_t WU_OFF  = 0;                 // bf16 [L,S,D]   262144
static constexpr size_t WG_OFF  = 262144;            // bf16 [L,D,D]  2097152
static constexpr size_t WOP_OFF = 2359296;           // bf16 [L,D,S]   262144
static constexpr size_t BU_OFF  = 2621440;           // fp32 [L,S]       1024
static constexpr size_t PART_OFF= 2622464;           // fp32 [8,32,512] 524288
static constexpr size_t Y_OFF   = 3146752;           // fp32 [B,D]      65536
static constexpr size_t X_OFF   = 3212288;           // fp32 [B,T,D] 134217728
static constexpr size_t XN_OFF  = X_OFF + 134217728; // chunk region starts here

extern "C" void kernel_launch(void* const* d_in, const int* in_sizes, int n_in,
                              void* d_out, int out_size, void* d_ws, size_t ws_size,
                              hipStream_t stream) {
  const int*   tok  = (const int*)d_in[0];
  const float* emb  = (const float*)d_in[1];
  const float* ln_w = (const float*)d_in[2];
  const float* ln_b = (const float*)d_in[3];
  const float* Wsp  = (const float*)d_in[4];
  const float* bsp  = (const float*)d_in[5];
  const float* Wip  = (const float*)d_in[6];
  const float* bip  = (const float*)d_in[7];
  const float* Wop  = (const float*)d_in[8];
  const float* bop  = (const float*)d_in[9];
  const float* Wg   = (const float*)d_in[10];
  const float* bg   = (const float*)d_in[11];
  const float* Am   = (const float*)d_in[12];
  const float* fw   = (const float*)d_in[13];
  const float* fb   = (const float*)d_in[14];
  const float* W1   = (const float*)d_in[15];
  const float* b1   = (const float*)d_in[16];
  const float* W2   = (const float*)d_in[17];
  const float* b2   = (const float*)d_in[18];

  char* ws = (char*)d_ws;
  unsigned short* Wu   = (unsigned short*)(ws + WU_OFF);
  unsigned short* WgB  = (unsigned short*)(ws + WG_OFF);
  unsigned short* WopB = (unsigned short*)(ws + WOP_OFF);
  float*          bu   = (float*)(ws + BU_OFF);
  float*          part = (float*)(ws + PART_OFF);
  float*          y    = (float*)(ws + Y_OFF);
  float*          x    = (float*)(ws + X_OFF);
  float*          outp = (float*)d_out;

  // chunking: per-chunk bytes = xn(1024*Mc) + u(256*Mc) + hs(128*Mc) = 1408*Mc
  int nch = 32;
  for (int c = 1; c <= 32; c <<= 1) {
    size_t Mc = (size_t)Mrows / c;
    if (XN_OFF + 1408ull * Mc <= ws_size) { nch = c; break; }
  }
  const int nb = Bn / nch;
  const size_t Mc = (size_t)Mrows / nch;
  unsigned short* xn = (unsigned short*)(ws + XN_OFF);
  float*          u  = (float*)(ws + XN_OFF + 1024ull * Mc);
  unsigned short* hs = (unsigned short*)(ws + XN_OFF + 1280ull * Mc);

  prep_wu<<<512, 256, 0, stream>>>(Wsp, Wip, bsp, bip, Wu, bu);
  cast_bf<<<4096, 256, 0, stream>>>(Wg, WgB, Lk * Dn * Dn);
  cast_bf<<<512, 256, 0, stream>>>(Wop, WopB, Lk * Dn * Sn);

  embed_kernel<<<Mrows * (Dn / 4) / 256, 256, 0, stream>>>(tok, emb, x);

  for (int l = 0; l < Lk; ++l) {
    for (int c = 0; c < nch; ++c) {
      float* xc = x + (size_t)c * Mc * Dn;
      ln_u_kernel<<<(int)(Mc / 32), 256, 0, stream>>>(
          xc, ln_w + l * Dn, ln_b + l * Dn, Wu + (size_t)l * Sn * Dn,
          bu + l * Sn, xn, u);
      scan_kernel<<<dim3(Tn / 64, nb), 64, 0, stream>>>(
          u, Am + (size_t)l * Sn * Sn, hs);
      gemm_gateop<<<dim3((int)(Mc / 128), Dn / 128), 512, 0, stream>>>(
          xn, hs, WgB + (size_t)l * Dn * Dn, WopB + (size_t)l * Dn * Sn,
          bg + l * Dn, bop + l * Dn, xc);
    }
  }

  final_ln_mean<<<dim3(8, Bn), 256, 0, stream>>>(x, fw, fb, part);
  reduce_y<<<Bn, 512, 0, stream>>>(part, y);
  head_kernel<<<Bn, 256, 0, stream>>>(y, W1, b1, W2, b2, outp);
}

// Round 6
// 760.703 us; speedup vs baseline: 1.3537x; 1.3537x over previous
//
#include <hip/hip_runtime.h>

// ---------------------------------------------------------------------------
// SimplifiedMambaModel on MI355X (gfx950)
// B=32 T=2048 D=512 S=64 L=4 V=32000 C=2
//  - residual stream x stored BF16 (halves dominant RMW traffic)
//  - bf16 MFMA (16x16x32), fp32 accumulate, fused epilogues
//  - gateop: r4-proven both-staged swizzled 4-wave structure + bf16 RMW
//  - ln_u: fused LN + u-projection, 32-row blocks (20 waves/CU)
//  - tanh-RNN scan over 64-step chunks (16-step warmup; contraction
//    sigma_max(A)~0.16 makes warm-start error ~1e-11)
// ---------------------------------------------------------------------------

#define DEV __device__ __forceinline__

typedef __attribute__((ext_vector_type(8))) short short8v;   // 8 x bf16
typedef __attribute__((ext_vector_type(4))) float f32x4;     // MFMA C/D frag

static constexpr int Bn = 32, Tn = 2048, Dn = 512, Sn = 64, Lk = 4;
static constexpr int Mrows = Bn * Tn;  // 65536

DEV unsigned short f2bf(float f) {          // RNE float->bf16
  unsigned u = __float_as_uint(f);
  u += 0x7fffu + ((u >> 16) & 1u);
  return (unsigned short)(u >> 16);
}
DEV float bf2f(unsigned short h) { return __uint_as_float(((unsigned)h) << 16); }

DEV void g2lds16(const void* g, void* l) {
  __builtin_amdgcn_global_load_lds(
      (const __attribute__((address_space(1))) void*)g,
      (__attribute__((address_space(3))) void*)l, 16, 0, 0);
}

// Stage a [ROWS x 64-bf16] tile with T2 XOR swizzle: LDS dest linear
// (global_load_lds requirement), global source column pre-swizzled so that
// LDS ushort (row, e) holds source element (row, e ^ ((row&7)<<3)).
// Readers XOR their FULL ushort column index with ((row&7)<<3).
template <int THREADS, int ROWS>
DEV void stage_sw(const char* gbase, size_t rowStride, size_t kOff, char* lds, int tid) {
#pragma unroll
  for (int r = 0; r < ROWS * 128 / (THREADS * 16); ++r) {
    int o = r * THREADS * 16 + tid * 16;
    int row = o >> 7, kb = o & 127;
    g2lds16(gbase + (size_t)row * rowStride + kOff + (size_t)(kb ^ ((row & 7) << 4)),
            lds + o);
  }
}

// ---------------------------------------------------------------------------
// Weight prep
// ---------------------------------------------------------------------------
__global__ void prep_wu(const float* __restrict__ Wsp, const float* __restrict__ Wip,
                        const float* __restrict__ bsp, const float* __restrict__ bip,
                        unsigned short* __restrict__ Wu, float* __restrict__ bu) {
  int i = blockIdx.x * 256 + threadIdx.x;
  if (i < Lk * Sn * Dn) Wu[i] = f2bf(Wsp[i] + Wip[i]);
  if (i < Lk * Sn) bu[i] = bsp[i] + bip[i];
}

__global__ void cast_bf(const float* __restrict__ src, unsigned short* __restrict__ dst, int n) {
  int i = blockIdx.x * 256 + threadIdx.x;
  if (i < n) dst[i] = f2bf(src[i]);
}

// ---------------------------------------------------------------------------
// Embedding gather: x[b,t,:] = bf16(emb[tok[b,t],:] * sqrt(512))
// one short8 (16B) per thread
// ---------------------------------------------------------------------------
__global__ __launch_bounds__(256) void embed_kernel(const int* __restrict__ tok,
                                                    const float* __restrict__ emb,
                                                    unsigned short* __restrict__ x) {
  const float scale = sqrtf(512.0f);
  size_t i = (size_t)blockIdx.x * 256 + threadIdx.x;   // short8 index
  int row = (int)(i >> 6);            // 64 short8 per row
  int c8  = (int)(i & 63);
  int t = tok[row];
  const float4* src = (const float4*)(emb + (size_t)t * Dn + c8 * 8);
  float4 a = src[0], b = src[1];
  short8v o;
  o[0] = (short)f2bf(a.x * scale); o[1] = (short)f2bf(a.y * scale);
  o[2] = (short)f2bf(a.z * scale); o[3] = (short)f2bf(a.w * scale);
  o[4] = (short)f2bf(b.x * scale); o[5] = (short)f2bf(b.y * scale);
  o[6] = (short)f2bf(b.z * scale); o[7] = (short)f2bf(b.w * scale);
  ((short8v*)x)[i] = o;
}

// ---------------------------------------------------------------------------
// Fused LayerNorm + u-projection.  32 rows/block, 256 threads (4 waves).
//   xn = LN(x)*g+b (bf16, kept in 32KB LDS, swizzled);  u = xn @ Wu^T + bu
// Wu (64KB) read direct from L2/L1.  5 blocks/CU -> 20 waves/CU.
// ---------------------------------------------------------------------------
__global__ __launch_bounds__(256) void ln_u_kernel(
    const unsigned short* __restrict__ x,   // [Mc,512] bf16
    const float* __restrict__ lnw, const float* __restrict__ lnb,
    const unsigned short* __restrict__ Wu,  // [64,512] bf16
    const float* __restrict__ bu,           // [64]
    unsigned short* __restrict__ xn,        // [Mc,512] bf16 out
    float* __restrict__ u) {                // [Mc,64]  fp32 out
  __shared__ __align__(16) unsigned short As[32 * 512];   // 32KB, XOR-swizzled
  const int tid = threadIdx.x, lane = tid & 63, w = tid >> 6;
  const int row0 = blockIdx.x * 32;
  const float4* wp = (const float4*)(lnw + lane * 8);
  const float4* bp = (const float4*)(lnb + lane * 8);
  float4 g0 = wp[0], g1 = wp[1], be0 = bp[0], be1 = bp[1];

#pragma unroll 2
  for (int i = 0; i < 8; ++i) {
    int row = w * 8 + i;
    size_t grow = (size_t)(row0 + row);
    short8v v = *(const short8v*)(x + grow * 512 + lane * 8);
    float f0 = bf2f((unsigned short)v[0]), f1 = bf2f((unsigned short)v[1]);
    float f2 = bf2f((unsigned short)v[2]), f3 = bf2f((unsigned short)v[3]);
    float f4 = bf2f((unsigned short)v[4]), f5 = bf2f((unsigned short)v[5]);
    float f6 = bf2f((unsigned short)v[6]), f7 = bf2f((unsigned short)v[7]);
    float s = (f0 + f1) + (f2 + f3) + (f4 + f5) + (f6 + f7);
    float q = f0*f0 + f1*f1 + f2*f2 + f3*f3 + f4*f4 + f5*f5 + f6*f6 + f7*f7;
#pragma unroll
    for (int m = 32; m >= 1; m >>= 1) { s += __shfl_xor(s, m); q += __shfl_xor(q, m); }
    float mean = s * (1.f / 512.f);
    float var  = q * (1.f / 512.f) - mean * mean;
    float rstd = 1.f / sqrtf(var + 1e-5f);
    short8v o;
    o[0] = (short)f2bf((f0 - mean) * rstd * g0.x + be0.x);
    o[1] = (short)f2bf((f1 - mean) * rstd * g0.y + be0.y);
    o[2] = (short)f2bf((f2 - mean) * rstd * g0.z + be0.z);
    o[3] = (short)f2bf((f3 - mean) * rstd * g0.w + be0.w);
    o[4] = (short)f2bf((f4 - mean) * rstd * g1.x + be1.x);
    o[5] = (short)f2bf((f5 - mean) * rstd * g1.y + be1.y);
    o[6] = (short)f2bf((f6 - mean) * rstd * g1.z + be1.z);
    o[7] = (short)f2bf((f7 - mean) * rstd * g1.w + be1.w);
    *(short8v*)&As[row * 512 + ((lane * 8) ^ ((row & 7) << 3))] = o;
    *(short8v*)(xn + grow * 512 + lane * 8) = o;
  }
  __syncthreads();

  // waves 2x2: wr rows (16), wc col-halves (32)
  const int wr = w >> 1, wc = w & 1;
  f32x4 acc[2] = {};
  const int rs = lane & 15, kx = (lane >> 4) * 8;
  const int key = (rs & 7) << 3;
  const int arow = (wr * 16 + rs) * 512;
#pragma unroll
  for (int kt = 0; kt < 16; ++kt) {
    short8v a = *(const short8v*)&As[arow + ((kt * 32 + kx) ^ key)];
#pragma unroll
    for (int n = 0; n < 2; ++n) {
      int col = wc * 32 + n * 16 + rs;
      short8v b = *(const short8v*)(Wu + (size_t)col * 512 + kt * 32 + kx);
      acc[n] = __builtin_amdgcn_mfma_f32_16x16x32_bf16(a, b, acc[n], 0, 0, 0);
    }
  }
  const int ccol = lane & 15, cr4 = (lane >> 4) * 4;
#pragma unroll
  for (int n = 0; n < 2; ++n) {
    int col = wc * 32 + n * 16 + ccol;
    float bv = bu[col];
#pragma unroll
    for (int j = 0; j < 4; ++j) {
      int row = wr * 16 + cr4 + j;
      u[(size_t)(row0 + row) * 64 + col] = acc[n][j] + bv;
    }
  }
}

// ---------------------------------------------------------------------------
// Fused gate + out-projection + residual (r4-proven structure, bf16 RMW):
//   x[r,c] += sigmoid(xn@Wg^T + bg)[r,c] * (hs@Wop^T + bop)[r,c]
// BM=BN=128, 4 waves (2x2), K=512 gate then K=64 out-proj, XOR-swizzled LDS.
// ---------------------------------------------------------------------------
__global__ __launch_bounds__(256) void gemm_gateop(
    const unsigned short* __restrict__ xn,   // [Mc,512] bf16
    const unsigned short* __restrict__ hs,   // [Mc,64]  bf16
    const unsigned short* __restrict__ Wg,   // [512,512] bf16
    const unsigned short* __restrict__ Wop,  // [512,64]  bf16
    const float* __restrict__ bg, const float* __restrict__ bop,
    unsigned short* __restrict__ xr) {       // [Mc,512] bf16 RMW
  __shared__ __align__(16) unsigned short As[128 * 64];
  __shared__ __align__(16) unsigned short Bs[128 * 64];
  const int tid = threadIdx.x, lane = tid & 63, wave = tid >> 6;
  const int wr = wave >> 1, wc = wave & 1;
  const int row0 = blockIdx.x * 128, col0 = blockIdx.y * 128;
  f32x4 accg[4][4] = {};
  f32x4 acco[4][4] = {};
  const int rs = lane & 15;
  const int swu = (rs & 7) << 3;

  const char* Ab = (const char*)(xn + (size_t)row0 * 512);
  const char* Bb = (const char*)(Wg + (size_t)col0 * 512);
  for (int kt = 0; kt < 512; kt += 64) {
    stage_sw<256, 128>(Ab, 1024, (size_t)kt * 2, (char*)As, tid);
    stage_sw<256, 128>(Bb, 1024, (size_t)kt * 2, (char*)Bs, tid);
    __syncthreads();
#pragma unroll
    for (int kk = 0; kk < 2; ++kk) {
      const int ks = (kk * 32 + (lane >> 4) * 8) ^ swu;
      short8v af[4], bfv[4];
#pragma unroll
      for (int m = 0; m < 4; ++m)
        af[m] = *(const short8v*)&As[(wr * 64 + m * 16 + rs) * 64 + ks];
#pragma unroll
      for (int n = 0; n < 4; ++n)
        bfv[n] = *(const short8v*)&Bs[(wc * 64 + n * 16 + rs) * 64 + ks];
#pragma unroll
      for (int m = 0; m < 4; ++m)
#pragma unroll
        for (int n = 0; n < 4; ++n)
          accg[m][n] = __builtin_amdgcn_mfma_f32_16x16x32_bf16(af[m], bfv[n], accg[m][n], 0, 0, 0);
    }
    __syncthreads();
  }

  // out-projection pass (K=64) reusing the same LDS tiles
  stage_sw<256, 128>((const char*)(hs + (size_t)row0 * 64), 128, 0, (char*)As, tid);
  stage_sw<256, 128>((const char*)(Wop + (size_t)col0 * 64), 128, 0, (char*)Bs, tid);
  __syncthreads();
#pragma unroll
  for (int kk = 0; kk < 2; ++kk) {
    const int ks = (kk * 32 + (lane >> 4) * 8) ^ swu;
    short8v af[4], bfv[4];
#pragma unroll
    for (int m = 0; m < 4; ++m)
      af[m] = *(const short8v*)&As[(wr * 64 + m * 16 + rs) * 64 + ks];
#pragma unroll
    for (int n = 0; n < 4; ++n)
      bfv[n] = *(const short8v*)&Bs[(wc * 64 + n * 16 + rs) * 64 + ks];
#pragma unroll
    for (int m = 0; m < 4; ++m)
#pragma unroll
      for (int n = 0; n < 4; ++n)
        acco[m][n] = __builtin_amdgcn_mfma_f32_16x16x32_bf16(af[m], bfv[n], acco[m][n], 0, 0, 0);
  }

  // epilogue: C/D layout col=lane&15, row=(lane>>4)*4+reg; bf16 RMW
  const int ccol = lane & 15, cr4 = (lane >> 4) * 4;
#pragma unroll
  for (int m = 0; m < 4; ++m)
#pragma unroll
    for (int n = 0; n < 4; ++n) {
      int gcol = col0 + wc * 64 + n * 16 + ccol;
      float bgv = bg[gcol], bov = bop[gcol];
#pragma unroll
      for (int j = 0; j < 4; ++j) {
        int grow = row0 + wr * 64 + m * 16 + cr4 + j;
        size_t idx = (size_t)grow * 512 + gcol;
        float gv = 1.f / (1.f + __expf(-(accg[m][n][j] + bgv)));
        float ov = acco[m][n][j] + bov;
        xr[idx] = f2bf(bf2f(xr[idx]) + gv * ov);
      }
    }
}

// ---------------------------------------------------------------------------
// Chunked tanh-RNN scan: one wave per (batch, 64-step chunk), 16-step warmup.
// ---------------------------------------------------------------------------
__global__ __launch_bounds__(64) void scan_kernel(const float* __restrict__ u,
                                                  const float* __restrict__ A,
                                                  unsigned short* __restrict__ hs) {
  const int l = threadIdx.x;
  const int b = blockIdx.y, c = blockIdx.x;
  __shared__ float h[Sn];
  h[l] = 0.f;

  float4 Ar[16];
  const float4* Arow = (const float4*)(A + (size_t)l * Sn);
#pragma unroll
  for (int i = 0; i < 16; ++i) Ar[i] = Arow[i];

  int t0 = c * 64 - 16; if (t0 < 0) t0 = 0;
  const int tw = c * 64, tend = c * 64 + 64;
  const float* ub = u + (size_t)b * Tn * Sn;
  unsigned short* hb = hs + (size_t)b * Tn * Sn;

  float uv = ub[(size_t)t0 * Sn + l];
  for (int t = t0; t < tend; ++t) {
    int tnext = t + 1 < Tn ? t + 1 : Tn - 1;
    float unext = ub[(size_t)tnext * Sn + l];
    const float4* h4 = (const float4*)h;
    float a0 = uv, a1 = 0.f, a2 = 0.f, a3 = 0.f;
#pragma unroll
    for (int i = 0; i < 16; i += 4) {
      float4 h0 = h4[i], h1 = h4[i + 1], h2 = h4[i + 2], h3 = h4[i + 3];
      a0 += Ar[i].x * h0.x + Ar[i].y * h0.y + Ar[i].z * h0.z + Ar[i].w * h0.w;
      a1 += Ar[i+1].x * h1.x + Ar[i+1].y * h1.y + Ar[i+1].z * h1.z + Ar[i+1].w * h1.w;
      a2 += Ar[i+2].x * h2.x + Ar[i+2].y * h2.y + Ar[i+2].z * h2.z + Ar[i+2].w * h2.w;
      a3 += Ar[i+3].x * h3.x + Ar[i+3].y * h3.y + Ar[i+3].z * h3.z + Ar[i+3].w * h3.w;
    }
    float sv = (a0 + a1) + (a2 + a3);
    sv = fminf(fmaxf(sv, -15.f), 15.f);
    float e = __expf(2.f * sv);
    float hn = __fdividef(e - 1.f, e + 1.f);   // tanh
    if (t >= tw) hb[(size_t)t * Sn + l] = f2bf(hn);
    h[l] = hn;          // single-wave lockstep
    uv = unext;
  }
}

// ---------------------------------------------------------------------------
// Final LN + partial mean (deterministic two-stage), bf16 x input
// ---------------------------------------------------------------------------
__global__ __launch_bounds__(256) void final_ln_mean(const unsigned short* __restrict__ x,
                                                     const float* __restrict__ fw,
                                                     const float* __restrict__ fb,
                                                     float* __restrict__ part) {
  const int b = blockIdx.y, chunk = blockIdx.x;
  const int wave = threadIdx.x >> 6, lane = threadIdx.x & 63;
  const float4* wp = (const float4*)(fw + lane * 8);
  const float4* bp = (const float4*)(fb + lane * 8);
  float4 w0 = wp[0], w1 = wp[1], bb0 = bp[0], bb1 = bp[1];
  float acc[8] = {};
  for (int it = 0; it < 64; ++it) {
    int t = chunk * 256 + it * 4 + wave;
    short8v v = *(const short8v*)(x + ((size_t)b * Tn + t) * Dn + lane * 8);
    float f0 = bf2f((unsigned short)v[0]), f1 = bf2f((unsigned short)v[1]);
    float f2 = bf2f((unsigned short)v[2]), f3 = bf2f((unsigned short)v[3]);
    float f4 = bf2f((unsigned short)v[4]), f5 = bf2f((unsigned short)v[5]);
    float f6 = bf2f((unsigned short)v[6]), f7 = bf2f((unsigned short)v[7]);
    float s = (f0 + f1) + (f2 + f3) + (f4 + f5) + (f6 + f7);
#pragma unroll
    for (int m = 32; m >= 1; m >>= 1) s += __shfl_xor(s, m);
    float mean = s * (1.f / 512.f);
    float d0 = f0 - mean, d1 = f1 - mean, d2 = f2 - mean, d3 = f3 - mean;
    float d4 = f4 - mean, d5 = f5 - mean, d6 = f6 - mean, d7 = f7 - mean;
    float q = d0*d0 + d1*d1 + d2*d2 + d3*d3 + d4*d4 + d5*d5 + d6*d6 + d7*d7;
#pragma unroll
    for (int m = 32; m >= 1; m >>= 1) q += __shfl_xor(q, m);
    float rstd = 1.f / sqrtf(q * (1.f / 512.f) + 1e-5f);
    acc[0] += d0 * rstd * w0.x + bb0.x;
    acc[1] += d1 * rstd * w0.y + bb0.y;
    acc[2] += d2 * rstd * w0.z + bb0.z;
    acc[3] += d3 * rstd * w0.w + bb0.w;
    acc[4] += d4 * rstd * w1.x + bb1.x;
    acc[5] += d5 * rstd * w1.y + bb1.y;
    acc[6] += d6 * rstd * w1.z + bb1.z;
    acc[7] += d7 * rstd * w1.w + bb1.w;
  }
  __shared__ float red[4][512];
#pragma unroll
  for (int j = 0; j < 8; ++j) red[wave][lane * 8 + j] = acc[j];
  __syncthreads();
#pragma unroll
  for (int cc = 0; cc < 2; ++cc) {
    int cidx = threadIdx.x * 2 + cc;
    part[((size_t)(chunk * Bn + b)) * Dn + cidx] =
        red[0][cidx] + red[1][cidx] + red[2][cidx] + red[3][cidx];
  }
}

__global__ __launch_bounds__(512) void reduce_y(const float* __restrict__ part,
                                                float* __restrict__ y) {
  int b = blockIdx.x, d = threadIdx.x;
  float s = 0.f;
#pragma unroll
  for (int ch = 0; ch < 8; ++ch) s += part[((size_t)(ch * Bn + b)) * Dn + d];
  y[b * Dn + d] = s * (1.f / 2048.f);
}

// ---------------------------------------------------------------------------
// Head: out[b,:] = relu(y @ W1^T + b1) @ W2^T + b2
// ---------------------------------------------------------------------------
__global__ __launch_bounds__(256) void head_kernel(const float* __restrict__ y,
                                                   const float* __restrict__ W1,
                                                   const float* __restrict__ b1,
                                                   const float* __restrict__ W2,
                                                   const float* __restrict__ b2,
                                                   float* __restrict__ out) {
  const int b = blockIdx.x, j = threadIdx.x;
  __shared__ float ybuf[Dn];
  ybuf[j] = y[(size_t)b * Dn + j];
  ybuf[j + 256] = y[(size_t)b * Dn + 256 + j];
  __syncthreads();
  const float4* wj = (const float4*)(W1 + (size_t)j * Dn);
  const float4* yb = (const float4*)ybuf;
  float a0 = 0.f, a1 = 0.f, a2 = 0.f, a3 = 0.f;
  for (int k = 0; k < 128; k += 4) {
    float4 q0 = wj[k], q1 = wj[k+1], q2 = wj[k+2], q3 = wj[k+3];
    float4 u0 = yb[k], u1 = yb[k+1], u2 = yb[k+2], u3 = yb[k+3];
    a0 += q0.x*u0.x + q0.y*u0.y + q0.z*u0.z + q0.w*u0.w;
    a1 += q1.x*u1.x + q1.y*u1.y + q1.z*u1.z + q1.w*u1.w;
    a2 += q2.x*u2.x + q2.y*u2.y + q2.z*u2.z + q2.w*u2.w;
    a3 += q3.x*u3.x + q3.y*u3.y + q3.z*u3.z + q3.w*u3.w;
  }
  float hv = fmaxf((a0 + a1) + (a2 + a3) + b1[j], 0.f);
  __shared__ float red[256];
  for (int c = 0; c < 2; ++c) {
    red[j] = hv * W2[c * 256 + j];
    __syncthreads();
    for (int s2 = 128; s2 > 0; s2 >>= 1) {
      if (j < s2) red[j] += red[j + s2];
      __syncthreads();
    }
    if (j == 0) out[b * 2 + c] = red[0] + b2[c];
    __syncthreads();
  }
}

// ---------------------------------------------------------------------------
// Workspace layout (bytes). Fixed region, then x (bf16), then chunk buffers.
// ---------------------------------------------------------------------------
static constexpr size_t WU_OFF  = 0;                 // bf16 [L,S,D]   262144
static constexpr size_t WG_OFF  = 262144;            // bf16 [L,D,D]  2097152
static constexpr size_t WOP_OFF = 2359296;           // bf16 [L,D,S]   262144
static constexpr size_t BU_OFF  = 2621440;           // fp32 [L,S]       1024
static constexpr size_t PART_OFF= 2622464;           // fp32 [8,32,512] 524288
static constexpr size_t Y_OFF   = 3146752;           // fp32 [B,D]      65536
static constexpr size_t X_OFF   = 3212288;           // bf16 [B,T,D]  67108864
static constexpr size_t XN_OFF  = X_OFF + 67108864;  // chunk region starts here

extern "C" void kernel_launch(void* const* d_in, const int* in_sizes, int n_in,
                              void* d_out, int out_size, void* d_ws, size_t ws_size,
                              hipStream_t stream) {
  const int*   tok  = (const int*)d_in[0];
  const float* emb  = (const float*)d_in[1];
  const float* ln_w = (const float*)d_in[2];
  const float* ln_b = (const float*)d_in[3];
  const float* Wsp  = (const float*)d_in[4];
  const float* bsp  = (const float*)d_in[5];
  const float* Wip  = (const float*)d_in[6];
  const float* bip  = (const float*)d_in[7];
  const float* Wop  = (const float*)d_in[8];
  const float* bop  = (const float*)d_in[9];
  const float* Wg   = (const float*)d_in[10];
  const float* bg   = (const float*)d_in[11];
  const float* Am   = (const float*)d_in[12];
  const float* fw   = (const float*)d_in[13];
  const float* fb   = (const float*)d_in[14];
  const float* W1   = (const float*)d_in[15];
  const float* b1   = (const float*)d_in[16];
  const float* W2   = (const float*)d_in[17];
  const float* b2   = (const float*)d_in[18];

  char* ws = (char*)d_ws;
  unsigned short* Wu   = (unsigned short*)(ws + WU_OFF);
  unsigned short* WgB  = (unsigned short*)(ws + WG_OFF);
  unsigned short* WopB = (unsigned short*)(ws + WOP_OFF);
  float*          bu   = (float*)(ws + BU_OFF);
  float*          part = (float*)(ws + PART_OFF);
  float*          y    = (float*)(ws + Y_OFF);
  unsigned short* x    = (unsigned short*)(ws + X_OFF);
  float*          outp = (float*)d_out;

  // chunking: per-chunk bytes = xn(1024*Mc) + u(256*Mc) + hs(128*Mc) = 1408*Mc
  int nch = 32;
  for (int c = 1; c <= 32; c <<= 1) {
    size_t Mc = (size_t)Mrows / c;
    if (XN_OFF + 1408ull * Mc <= ws_size) { nch = c; break; }
  }
  const int nb = Bn / nch;
  const size_t Mc = (size_t)Mrows / nch;
  unsigned short* xn = (unsigned short*)(ws + XN_OFF);
  float*          u  = (float*)(ws + XN_OFF + 1024ull * Mc);
  unsigned short* hs = (unsigned short*)(ws + XN_OFF + 1280ull * Mc);

  prep_wu<<<512, 256, 0, stream>>>(Wsp, Wip, bsp, bip, Wu, bu);
  cast_bf<<<4096, 256, 0, stream>>>(Wg, WgB, Lk * Dn * Dn);
  cast_bf<<<512, 256, 0, stream>>>(Wop, WopB, Lk * Dn * Sn);

  embed_kernel<<<Mrows * (Dn / 8) / 256, 256, 0, stream>>>(tok, emb, x);

  for (int l = 0; l < Lk; ++l) {
    for (int c = 0; c < nch; ++c) {
      unsigned short* xc = x + (size_t)c * Mc * Dn;
      ln_u_kernel<<<(int)(Mc / 32), 256, 0, stream>>>(
          xc, ln_w + l * Dn, ln_b + l * Dn, Wu + (size_t)l * Sn * Dn,
          bu + l * Sn, xn, u);
      scan_kernel<<<dim3(Tn / 64, nb), 64, 0, stream>>>(
          u, Am + (size_t)l * Sn * Sn, hs);
      gemm_gateop<<<dim3((int)(Mc / 128), Dn / 128), 256, 0, stream>>>(
          xn, hs, WgB + (size_t)l * Dn * Dn, WopB + (size_t)l * Dn * Sn,
          bg + l * Dn, bop + l * Dn, xc);
    }
  }

  final_ln_mean<<<dim3(8, Bn), 256, 0, stream>>>(x, fw, fb, part);
  reduce_y<<<Bn, 512, 0, stream>>>(part, y);
  head_kernel<<<Bn, 256, 0, stream>>>(y, W1, b1, W2, b2, outp);
}